// Round 1
// baseline (382.527 us; speedup 1.0000x reference)
//
#include <hip/hip_runtime.h>
#include <hip/hip_bf16.h>
#include <math.h>

// Problem constants (fixed by the reference file): B=1, N=2048, V=1, H=W=128.
#define NMAX 2048
#define IMG_W 128
#define IMG_H 128
#define CHUNK 256

// ---------------------------------------------------------------------------
// Kernel 1: preprocess all gaussians + bitonic sort by camera-z + write
// sorted SoA into workspace. Single block of 1024 threads.
// ws layout (floats): [0..10*NMAX) unsorted SoA, [10*NMAX..20*NMAX) sorted SoA
// SoA order: u, v, ia, ib, ic, op, cr, cg, cb, z
// ---------------------------------------------------------------------------
__global__ __launch_bounds__(1024) void prep_sort_kernel(
    const float* __restrict__ xyz, const float* __restrict__ feat,
    const float* __restrict__ scal, const float* __restrict__ rot,
    const float* __restrict__ opac, const float* __restrict__ c2w,
    const float* __restrict__ intr, const int* __restrict__ nearp,
    const int* __restrict__ farp, float* __restrict__ ws, int N)
{
    __shared__ float key[NMAX];
    __shared__ int   val[NMAX];
    const int t = threadIdx.x;

    // Affine inverse of c2w (last row assumed [0,0,0,1], true for this input).
    const float A00=c2w[0], A01=c2w[1], A02=c2w[2],  b0=c2w[3];
    const float A10=c2w[4], A11=c2w[5], A12=c2w[6],  b1=c2w[7];
    const float A20=c2w[8], A21=c2w[9], A22=c2w[10], b2=c2w[11];
    const float detA = A00*(A11*A22-A12*A21) - A01*(A10*A22-A12*A20)
                     + A02*(A10*A21-A11*A20);
    const float id = 1.0f/detA;
    const float R00 =  (A11*A22-A12*A21)*id;
    const float R01 = -(A01*A22-A02*A21)*id;
    const float R02 =  (A01*A12-A02*A11)*id;
    const float R10 = -(A10*A22-A12*A20)*id;
    const float R11 =  (A00*A22-A02*A20)*id;
    const float R12 = -(A00*A12-A02*A10)*id;
    const float R20 =  (A10*A21-A11*A20)*id;
    const float R21 = -(A00*A21-A01*A20)*id;
    const float R22 =  (A00*A11-A01*A10)*id;
    const float t0 = -(R00*b0 + R01*b1 + R02*b2);
    const float t1 = -(R10*b0 + R11*b1 + R12*b2);
    const float t2 = -(R20*b0 + R21*b1 + R22*b2);

    const float fx=intr[0], fy=intr[1], cx=intr[2], cy=intr[3];
    const float nearf = (float)nearp[0], farf = (float)farp[0];

    float* Uu = ws + 0*NMAX;  float* Vv = ws + 1*NMAX;
    float* Ia = ws + 2*NMAX;  float* Ib = ws + 3*NMAX;
    float* Ic = ws + 4*NMAX;  float* Op = ws + 5*NMAX;
    float* Cr = ws + 6*NMAX;  float* Cg = ws + 7*NMAX;
    float* Cb = ws + 8*NMAX;  float* Zz = ws + 9*NMAX;
    float* S  = ws + 10*NMAX;

    for (int g = t; g < NMAX; g += blockDim.x) {
        if (g < N) {
            float qw=rot[g*4+0], qx=rot[g*4+1], qy=rot[g*4+2], qz=rot[g*4+3];
            float qn = sqrtf(qw*qw+qx*qx+qy*qy+qz*qz) + 1e-8f;
            float iq = 1.0f/qn;
            qw*=iq; qx*=iq; qy*=iq; qz*=iq;
            float r00=1.f-2.f*(qy*qy+qz*qz), r01=2.f*(qx*qy-qw*qz), r02=2.f*(qx*qz+qw*qy);
            float r10=2.f*(qx*qy+qw*qz), r11=1.f-2.f*(qx*qx+qz*qz), r12=2.f*(qy*qz-qw*qx);
            float r20=2.f*(qx*qz-qw*qy), r21=2.f*(qy*qz+qw*qx), r22=1.f-2.f*(qx*qx+qy*qy);
            float s0=scal[g*3], s1=scal[g*3+1], s2=scal[g*3+2];
            // M = R * diag(s) (scale columns)
            float m00=r00*s0, m01=r01*s1, m02=r02*s2;
            float m10=r10*s0, m11=r11*s1, m12=r12*s2;
            float m20=r20*s0, m21=r21*s1, m22=r22*s2;
            // U3 = Rw @ M  (so cov2d = (J U3)(J U3)^T)
            float u00=R00*m00+R01*m10+R02*m20, u01=R00*m01+R01*m11+R02*m21, u02=R00*m02+R01*m12+R02*m22;
            float u10=R10*m00+R11*m10+R12*m20, u11=R10*m01+R11*m11+R12*m21, u12=R10*m02+R11*m12+R12*m22;
            float u20=R20*m00+R21*m10+R22*m20, u21=R20*m01+R21*m11+R22*m21, u22=R20*m02+R21*m12+R22*m22;
            float x0=xyz[g*3], x1=xyz[g*3+1], x2=xyz[g*3+2];
            float p0=R00*x0+R01*x1+R02*x2+t0;
            float p1=R10*x0+R11*x1+R12*x2+t1;
            float p2=R20*x0+R21*x1+R22*x2+t2;
            float z = p2;
            float zs = fmaxf(z, 1e-4f);
            float invzs = 1.0f/zs;
            float u = fx*p0*invzs + cx;
            float v = fy*p1*invzs + cy;
            float j00 = fx*invzs, j02 = -fx*p0*invzs*invzs;
            float j11 = fy*invzs, j12 = -fy*p1*invzs*invzs;
            // T (2x3) = J @ U3
            float T00=j00*u00+j02*u20, T01=j00*u01+j02*u21, T02=j00*u02+j02*u22;
            float T10=j11*u10+j12*u20, T11=j11*u11+j12*u21, T12=j11*u12+j12*u22;
            float a  = T00*T00+T01*T01+T02*T02 + 0.3f;
            float bb = T00*T10+T01*T11+T02*T12;
            float c  = T10*T10+T11*T11+T12*T12 + 0.3f;
            float dt = a*c - bb*bb;
            bool  vdet = dt > 1e-12f;
            float du = vdet ? dt : 1.0f;
            float inv = 1.0f/du;
            bool valid = (z > nearf) && (z < farf) && vdet;
            Uu[g]=u; Vv[g]=v;
            Ia[g]=c*inv; Ib[g]=-bb*inv; Ic[g]=a*inv;
            Op[g]= valid ? opac[g] : 0.0f;
            Cr[g]=fmaxf(0.28209479177387814f*feat[g*3+0]+0.5f, 0.0f);
            Cg[g]=fmaxf(0.28209479177387814f*feat[g*3+1]+0.5f, 0.0f);
            Cb[g]=fmaxf(0.28209479177387814f*feat[g*3+2]+0.5f, 0.0f);
            Zz[g]=z;
            key[g]=z; val[g]=g;
        } else {
            Uu[g]=0.f;Vv[g]=0.f;Ia[g]=0.f;Ib[g]=0.f;Ic[g]=0.f;
            Op[g]=0.f;Cr[g]=0.f;Cg[g]=0.f;Cb[g]=0.f;Zz[g]=0.f;
            key[g]=3.4e38f; val[g]=g;
        }
    }
    __syncthreads();

    // Bitonic sort ascending on (key=z, val=index).
    for (int k = 2; k <= NMAX; k <<= 1) {
        for (int j = k >> 1; j > 0; j >>= 1) {
            for (int i = t; i < NMAX; i += blockDim.x) {
                int ixj = i ^ j;
                if (ixj > i) {
                    bool up = ((i & k) == 0);
                    float ki = key[i], kj = key[ixj];
                    if ((ki > kj) == up) {
                        key[i]=kj; key[ixj]=ki;
                        int tv=val[i]; val[i]=val[ixj]; val[ixj]=tv;
                    }
                }
            }
            __syncthreads();
        }
    }

    // Gather into sorted SoA.
    for (int s = t; s < NMAX; s += blockDim.x) {
        int g = val[s];
        S[0*NMAX+s]=Uu[g]; S[1*NMAX+s]=Vv[g];
        S[2*NMAX+s]=Ia[g]; S[3*NMAX+s]=Ib[g]; S[4*NMAX+s]=Ic[g];
        S[5*NMAX+s]=Op[g];
        S[6*NMAX+s]=Cr[g]; S[7*NMAX+s]=Cg[g]; S[8*NMAX+s]=Cb[g];
        S[9*NMAX+s]=Zz[g];
    }
}

// ---------------------------------------------------------------------------
// Kernel 2: per-pixel front-to-back compositing over sorted gaussians.
// 64 blocks x 256 threads; each block = 16x16 pixel tile; gaussians staged
// through LDS in chunks of 256 (broadcast reads, conflict-free).
// ---------------------------------------------------------------------------
__global__ __launch_bounds__(256) void render_kernel(
    const float* __restrict__ ws, float* __restrict__ out)
{
    const float* S = ws + 10*NMAX;
    __shared__ float su[CHUNK], sv[CHUNK], sia[CHUNK], sib[CHUNK], sic[CHUNK],
                     sop[CHUNK], scr[CHUNK], scg[CHUNK], scb[CHUNK], sz[CHUNK];
    const int t = threadIdx.x;
    const int tilex = blockIdx.x & (IMG_W/16 - 1);
    const int tiley = blockIdx.x / (IMG_W/16);
    const int x = tilex*16 + (t & 15);
    const int y = tiley*16 + (t >> 4);
    const float px = x + 0.5f, py = y + 0.5f;

    float T = 1.0f, rr=0.f, gg=0.f, bb=0.f, dd=0.f;

    for (int base = 0; base < NMAX; base += CHUNK) {
        int g = base + t;
        su[t]  = S[0*NMAX+g]; sv[t]  = S[1*NMAX+g];
        sia[t] = S[2*NMAX+g]; sib[t] = S[3*NMAX+g]; sic[t] = S[4*NMAX+g];
        sop[t] = S[5*NMAX+g];
        scr[t] = S[6*NMAX+g]; scg[t] = S[7*NMAX+g]; scb[t] = S[8*NMAX+g];
        sz[t]  = S[9*NMAX+g];
        __syncthreads();

        if (T >= 1e-5f) {
            for (int j = 0; j < CHUNK; ++j) {
                float dx = px - su[j], dy = py - sv[j];
                float pw = -0.5f*(sia[j]*dx*dx + sic[j]*dy*dy) - sib[j]*dx*dy;
                float al = fminf(sop[j]*__expf(fminf(pw, 0.0f)), 0.99f);
                if (pw <= 0.0f && al >= (1.0f/255.0f)) {
                    float w = T*al;
                    rr += w*scr[j]; gg += w*scg[j]; bb += w*scb[j]; dd += w*sz[j];
                    T *= (1.0f - al);
                    if (T < 1e-5f) break;
                }
            }
        }
        int alive = __syncthreads_count(T >= 1e-5f);  // also barrier before next stage
        if (alive == 0) break;
    }

    const int HW = IMG_W*IMG_H;
    const int pix = y*IMG_W + x;
    out[0*HW+pix] = rr;
    out[1*HW+pix] = gg;
    out[2*HW+pix] = bb;
    out[3*HW+pix] = dd;
}

extern "C" void kernel_launch(void* const* d_in, const int* in_sizes, int n_in,
                              void* d_out, int out_size, void* d_ws, size_t ws_size,
                              hipStream_t stream) {
    const float* xyz  = (const float*)d_in[0];
    const float* feat = (const float*)d_in[1];
    const float* scal = (const float*)d_in[2];
    const float* rot  = (const float*)d_in[3];
    const float* opac = (const float*)d_in[4];
    const float* c2w  = (const float*)d_in[5];
    const float* intr = (const float*)d_in[6];
    const int*   nearp = (const int*)d_in[10];
    const int*   farp  = (const int*)d_in[11];
    float* ws  = (float*)d_ws;
    float* out = (float*)d_out;
    const int N = in_sizes[0] / 3;   // B=1 -> N gaussians

    prep_sort_kernel<<<1, 1024, 0, stream>>>(xyz, feat, scal, rot, opac,
                                             c2w, intr, nearp, farp, ws, N);
    const int ntiles = (IMG_W/16) * (IMG_H/16);  // 64
    render_kernel<<<ntiles, 256, 0, stream>>>(ws, out);
}

// Round 2
// 170.818 us; speedup vs baseline: 2.2394x; 2.2394x over previous
//
#include <hip/hip_runtime.h>
#include <hip/hip_bf16.h>
#include <math.h>

// Problem constants (fixed by the reference file): B=1, N=2048, V=1, H=W=128.
#define NMAX 2048
#define IMG_W 128
#define IMG_H 128
#define TILE 16
#define CHUNK 256

// ws layout (floats): [0..10*NMAX) unsorted SoA, [10*NMAX..20*NMAX) sorted SoA
// SoA order: u, v, ia, ib, ic, op, cr, cg, cb, z

// ---------------------------------------------------------------------------
// Kernel A: per-gaussian preprocessing (8 blocks x 256).
// ---------------------------------------------------------------------------
__global__ __launch_bounds__(256) void prep_kernel(
    const float* __restrict__ xyz, const float* __restrict__ feat,
    const float* __restrict__ scal, const float* __restrict__ rot,
    const float* __restrict__ opac, const float* __restrict__ c2w,
    const float* __restrict__ intr, const int* __restrict__ nearp,
    const int* __restrict__ farp, float* __restrict__ ws, int N)
{
    const int g = blockIdx.x * blockDim.x + threadIdx.x;
    if (g >= NMAX) return;

    float* U = ws;   // 10 arrays of NMAX

    if (g >= N) {
        #pragma unroll
        for (int k = 0; k < 9; ++k) U[k*NMAX+g] = 0.0f;
        U[9*NMAX+g] = 3.4e38f;   // z key: pads sort last
        return;
    }

    // Affine inverse of c2w (last row [0,0,0,1] for this input).
    const float A00=c2w[0], A01=c2w[1], A02=c2w[2],  b0=c2w[3];
    const float A10=c2w[4], A11=c2w[5], A12=c2w[6],  b1=c2w[7];
    const float A20=c2w[8], A21=c2w[9], A22=c2w[10], b2=c2w[11];
    const float detA = A00*(A11*A22-A12*A21) - A01*(A10*A22-A12*A20)
                     + A02*(A10*A21-A11*A20);
    const float id = 1.0f/detA;
    const float R00 =  (A11*A22-A12*A21)*id;
    const float R01 = -(A01*A22-A02*A21)*id;
    const float R02 =  (A01*A12-A02*A11)*id;
    const float R10 = -(A10*A22-A12*A20)*id;
    const float R11 =  (A00*A22-A02*A20)*id;
    const float R12 = -(A00*A12-A02*A10)*id;
    const float R20 =  (A10*A21-A11*A20)*id;
    const float R21 = -(A00*A21-A01*A20)*id;
    const float R22 =  (A00*A11-A01*A10)*id;
    const float t0 = -(R00*b0 + R01*b1 + R02*b2);
    const float t1 = -(R10*b0 + R11*b1 + R12*b2);
    const float t2 = -(R20*b0 + R21*b1 + R22*b2);

    const float fx=intr[0], fy=intr[1], cx=intr[2], cy=intr[3];
    const float nearf = (float)nearp[0], farf = (float)farp[0];

    float qw=rot[g*4+0], qx=rot[g*4+1], qy=rot[g*4+2], qz=rot[g*4+3];
    float iq = 1.0f/(sqrtf(qw*qw+qx*qx+qy*qy+qz*qz) + 1e-8f);
    qw*=iq; qx*=iq; qy*=iq; qz*=iq;
    float r00=1.f-2.f*(qy*qy+qz*qz), r01=2.f*(qx*qy-qw*qz), r02=2.f*(qx*qz+qw*qy);
    float r10=2.f*(qx*qy+qw*qz), r11=1.f-2.f*(qx*qx+qz*qz), r12=2.f*(qy*qz-qw*qx);
    float r20=2.f*(qx*qz-qw*qy), r21=2.f*(qy*qz+qw*qx), r22=1.f-2.f*(qx*qx+qy*qy);
    float s0=scal[g*3], s1=scal[g*3+1], s2=scal[g*3+2];
    float m00=r00*s0, m01=r01*s1, m02=r02*s2;
    float m10=r10*s0, m11=r11*s1, m12=r12*s2;
    float m20=r20*s0, m21=r21*s1, m22=r22*s2;
    // U3 = Rw @ M  (cov2d = (J U3)(J U3)^T)
    float u00=R00*m00+R01*m10+R02*m20, u01=R00*m01+R01*m11+R02*m21, u02=R00*m02+R01*m12+R02*m22;
    float u10=R10*m00+R11*m10+R12*m20, u11=R10*m01+R11*m11+R12*m21, u12=R10*m02+R11*m12+R12*m22;
    float u20=R20*m00+R21*m10+R22*m20, u21=R20*m01+R21*m11+R22*m21, u22=R20*m02+R21*m12+R22*m22;
    float x0=xyz[g*3], x1=xyz[g*3+1], x2=xyz[g*3+2];
    float p0=R00*x0+R01*x1+R02*x2+t0;
    float p1=R10*x0+R11*x1+R12*x2+t1;
    float p2=R20*x0+R21*x1+R22*x2+t2;
    float z = p2;
    float zs = fmaxf(z, 1e-4f);
    float invzs = 1.0f/zs;
    float u = fx*p0*invzs + cx;
    float v = fy*p1*invzs + cy;
    float j00 = fx*invzs, j02 = -fx*p0*invzs*invzs;
    float j11 = fy*invzs, j12 = -fy*p1*invzs*invzs;
    float T00=j00*u00+j02*u20, T01=j00*u01+j02*u21, T02=j00*u02+j02*u22;
    float T10=j11*u10+j12*u20, T11=j11*u11+j12*u21, T12=j11*u12+j12*u22;
    float a  = T00*T00+T01*T01+T02*T02 + 0.3f;
    float bb = T00*T10+T01*T11+T02*T12;
    float c  = T10*T10+T11*T11+T12*T12 + 0.3f;
    float dt = a*c - bb*bb;
    bool  vdet = dt > 1e-12f;
    float inv = 1.0f/(vdet ? dt : 1.0f);
    bool valid = (z > nearf) && (z < farf) && vdet;

    U[0*NMAX+g]=u;       U[1*NMAX+g]=v;
    U[2*NMAX+g]=c*inv;   U[3*NMAX+g]=-bb*inv;  U[4*NMAX+g]=a*inv;
    U[5*NMAX+g]= valid ? opac[g] : 0.0f;
    U[6*NMAX+g]=fmaxf(0.28209479177387814f*feat[g*3+0]+0.5f, 0.0f);
    U[7*NMAX+g]=fmaxf(0.28209479177387814f*feat[g*3+1]+0.5f, 0.0f);
    U[8*NMAX+g]=fmaxf(0.28209479177387814f*feat[g*3+2]+0.5f, 0.0f);
    U[9*NMAX+g]=z;
}

// ---------------------------------------------------------------------------
// Kernel B: stable rank-counting argsort by z + scatter into sorted SoA.
// Barrier-free counting over an LDS-resident z array (8 blocks x 256).
// Exactly reproduces jnp.argsort (stable) incl. tie-break by index.
// ---------------------------------------------------------------------------
__global__ __launch_bounds__(256) void sort_kernel(float* __restrict__ ws)
{
    __shared__ float lz[NMAX];
    const float* U = ws;
    float* S = ws + 10*NMAX;
    const int t = threadIdx.x;
    for (int i = t; i < NMAX; i += blockDim.x) lz[i] = U[9*NMAX+i];
    __syncthreads();

    const int g = blockIdx.x * blockDim.x + t;
    const float zg = lz[g];
    int rank = 0;
    #pragma unroll 8
    for (int j = 0; j < NMAX; ++j) {
        float zj = lz[j];
        rank += ((zj < zg) || (zj == zg && j < g)) ? 1 : 0;
    }
    #pragma unroll
    for (int k = 0; k < 10; ++k) S[k*NMAX+rank] = U[k*NMAX+g];
}

// ---------------------------------------------------------------------------
// Kernel C: per-tile culled compositing. 64 blocks x 256 (16x16 tiles).
// Per 256-gaussian chunk: each thread tests its gaussian's alpha>=1/255
// ellipse bbox vs the tile, stable ballot-compaction into LDS (depth order
// preserved), then all pixels composite only the survivors.
// ---------------------------------------------------------------------------
__global__ __launch_bounds__(256) void render_kernel(
    const float* __restrict__ ws, float* __restrict__ out)
{
    const float* S = ws + 10*NMAX;
    __shared__ float su[CHUNK], sv[CHUNK], sia[CHUNK], sib[CHUNK], sic[CHUNK],
                     sop[CHUNK], scr[CHUNK], scg[CHUNK], scb[CHUNK], sz[CHUNK];
    __shared__ int wcnt[4];

    const int t = threadIdx.x;
    const int tilex = blockIdx.x & (IMG_W/TILE - 1);
    const int tiley = blockIdx.x / (IMG_W/TILE);
    const int x = tilex*TILE + (t & 15);
    const int y = tiley*TILE + (t >> 4);
    const float px = x + 0.5f, py = y + 0.5f;
    // Pixel-center extents of this tile:
    const float tx0 = tilex*TILE + 0.5f, tx1 = tx0 + (TILE-1);
    const float ty0 = tiley*TILE + 0.5f, ty1 = ty0 + (TILE-1);

    const int lane = t & 63, w = t >> 6;
    const unsigned long long lmask = (1ull << lane) - 1ull;

    float T = 1.0f, rr=0.f, gg=0.f, bb=0.f, dd=0.f;

    for (int base = 0; base < NMAX; base += CHUNK) {
        const int g = base + t;
        // --- cull: does this gaussian's alpha>=1/255 ellipse touch the tile?
        float u  = S[0*NMAX+g], v  = S[1*NMAX+g];
        float ia = S[2*NMAX+g], ib = S[3*NMAX+g], ic = S[4*NMAX+g];
        float op = S[5*NMAX+g];
        bool pred = false;
        float tau = 2.0f*__logf(255.0f*op) + 0.02f;  // +eps: conservative vs exp/log rounding
        if (tau > 0.0f) {
            float detC = ia*ic - ib*ib;     // = 1/det(cov2d) > 0 for valid
            float inv  = 1.0f/detC;
            float ru = sqrtf(tau * ic * inv);   // tau * Sigma_xx
            float rv = sqrtf(tau * ia * inv);   // tau * Sigma_yy
            pred = (u + ru >= tx0) && (u - ru <= tx1) &&
                   (v + rv >= ty0) && (v - rv <= ty1);
        }
        // --- stable compaction (depth order preserved)
        unsigned long long m = __ballot(pred);
        if (lane == 0) wcnt[w] = __popcll(m);
        __syncthreads();
        int off = 0;
        #pragma unroll
        for (int i = 0; i < 4; ++i) if (i < w) off += wcnt[i];
        const int total = wcnt[0]+wcnt[1]+wcnt[2]+wcnt[3];
        if (pred) {
            int p = off + __popcll(m & lmask);
            su[p]=u; sv[p]=v; sia[p]=ia; sib[p]=ib; sic[p]=ic; sop[p]=op;
            scr[p]=S[6*NMAX+g]; scg[p]=S[7*NMAX+g]; scb[p]=S[8*NMAX+g]; sz[p]=S[9*NMAX+g];
        }
        __syncthreads();

        // --- composite survivors, front-to-back
        if (T >= 1e-5f) {
            for (int j = 0; j < total; ++j) {
                float dx = px - su[j], dy = py - sv[j];
                float pw = -0.5f*(sia[j]*dx*dx + sic[j]*dy*dy) - sib[j]*dx*dy;
                float al = fminf(sop[j]*__expf(fminf(pw, 0.0f)), 0.99f);
                if (pw <= 0.0f && al >= (1.0f/255.0f)) {
                    float wg = T*al;
                    rr += wg*scr[j]; gg += wg*scg[j]; bb += wg*scb[j]; dd += wg*sz[j];
                    T *= (1.0f - al);
                    if (T < 1e-5f) break;
                }
            }
        }
        int alive = __syncthreads_count(T >= 1e-5f);  // barrier before LDS reuse
        if (alive == 0) break;
    }

    const int HW = IMG_W*IMG_H;
    const int pix = y*IMG_W + x;
    out[0*HW+pix] = rr;
    out[1*HW+pix] = gg;
    out[2*HW+pix] = bb;
    out[3*HW+pix] = dd;
}

extern "C" void kernel_launch(void* const* d_in, const int* in_sizes, int n_in,
                              void* d_out, int out_size, void* d_ws, size_t ws_size,
                              hipStream_t stream) {
    const float* xyz  = (const float*)d_in[0];
    const float* feat = (const float*)d_in[1];
    const float* scal = (const float*)d_in[2];
    const float* rot  = (const float*)d_in[3];
    const float* opac = (const float*)d_in[4];
    const float* c2w  = (const float*)d_in[5];
    const float* intr = (const float*)d_in[6];
    const int*   nearp = (const int*)d_in[10];
    const int*   farp  = (const int*)d_in[11];
    float* ws  = (float*)d_ws;
    float* out = (float*)d_out;
    const int N = in_sizes[0] / 3;

    prep_kernel<<<NMAX/256, 256, 0, stream>>>(xyz, feat, scal, rot, opac,
                                              c2w, intr, nearp, farp, ws, N);
    sort_kernel<<<NMAX/256, 256, 0, stream>>>(ws);
    const int ntiles = (IMG_W/TILE) * (IMG_H/TILE);  // 64
    render_kernel<<<ntiles, 256, 0, stream>>>(ws, out);
}

// Round 3
// 106.252 us; speedup vs baseline: 3.6002x; 1.6077x over previous
//
#include <hip/hip_runtime.h>
#include <hip/hip_bf16.h>
#include <math.h>

// Problem constants (fixed by the reference file): B=1, N=2048, V=1, H=W=128.
#define NMAX 2048
#define IMG_W 128
#define IMG_H 128
#define TILE 8            // 8x8 pixel tiles -> 16x16 = 256 blocks (all CUs)

// ---------------------------------------------------------------------------
// Single fused kernel: each block owns an 8x8 pixel tile.
//   Phase 1: all 256 threads cooperatively preprocess all 2048 gaussians
//            into block-local LDS SoA (recomputation is ~free: 0.1 GFLOP
//            aggregate across 256 blocks).
//   Phase 2: cull gaussians whose alpha>=1/255 ellipse bbox misses the tile;
//            append survivor keys (z-bits<<32 | idx) to an LDS list.
//   Phase 3: stable rank-counting sort of survivor keys (broadcast LDS
//            reads, unique keys -> exact rank; idx low-bits = stable
//            tie-break identical to jnp.argsort).
//   Phase 4: threads 0..63 composite their pixel front-to-back. No barriers,
//            all data in LDS, early exit at T<1e-5.
// LDS: 10*2048*4 (params) + 2048*8 (keys) + 2048*4 (sidx) ~= 104 KB < 160 KB.
// ---------------------------------------------------------------------------
__global__ __launch_bounds__(256) void fused_render_kernel(
    const float* __restrict__ xyz, const float* __restrict__ feat,
    const float* __restrict__ scal, const float* __restrict__ rot,
    const float* __restrict__ opac, const float* __restrict__ c2w,
    const float* __restrict__ intr, const int* __restrict__ nearp,
    const int* __restrict__ farp, float* __restrict__ out, int N)
{
    __shared__ float pu[NMAX], pv[NMAX], pia[NMAX], pib[NMAX], pic[NMAX],
                     pop[NMAX], pcr[NMAX], pcg[NMAX], pcb[NMAX], pz[NMAX];
    __shared__ unsigned long long keys[NMAX];
    __shared__ int sidx[NMAX];
    __shared__ int cnt;

    const int t = threadIdx.x;
    if (t == 0) cnt = 0;

    // ---- camera setup (uniform across threads; scalar regs) ----
    const float A00=c2w[0], A01=c2w[1], A02=c2w[2],  b0=c2w[3];
    const float A10=c2w[4], A11=c2w[5], A12=c2w[6],  b1=c2w[7];
    const float A20=c2w[8], A21=c2w[9], A22=c2w[10], b2=c2w[11];
    const float detA = A00*(A11*A22-A12*A21) - A01*(A10*A22-A12*A20)
                     + A02*(A10*A21-A11*A20);
    const float id = 1.0f/detA;
    const float R00 =  (A11*A22-A12*A21)*id;
    const float R01 = -(A01*A22-A02*A21)*id;
    const float R02 =  (A01*A12-A02*A11)*id;
    const float R10 = -(A10*A22-A12*A20)*id;
    const float R11 =  (A00*A22-A02*A20)*id;
    const float R12 = -(A00*A12-A02*A10)*id;
    const float R20 =  (A10*A21-A11*A20)*id;
    const float R21 = -(A00*A21-A01*A20)*id;
    const float R22 =  (A00*A11-A01*A10)*id;
    const float t0 = -(R00*b0 + R01*b1 + R02*b2);
    const float t1 = -(R10*b0 + R11*b1 + R12*b2);
    const float t2 = -(R20*b0 + R21*b1 + R22*b2);
    const float fx=intr[0], fy=intr[1], cx=intr[2], cy=intr[3];
    const float nearf = (float)nearp[0], farf = (float)farp[0];

    // ---- phase 1: preprocess all gaussians into LDS ----
    #pragma unroll
    for (int i = 0; i < NMAX/256; ++i) {
        const int g = i*256 + t;
        if (g < N) {
            float qw=rot[g*4+0], qx=rot[g*4+1], qy=rot[g*4+2], qz=rot[g*4+3];
            float iq = 1.0f/(sqrtf(qw*qw+qx*qx+qy*qy+qz*qz) + 1e-8f);
            qw*=iq; qx*=iq; qy*=iq; qz*=iq;
            float r00=1.f-2.f*(qy*qy+qz*qz), r01=2.f*(qx*qy-qw*qz), r02=2.f*(qx*qz+qw*qy);
            float r10=2.f*(qx*qy+qw*qz), r11=1.f-2.f*(qx*qx+qz*qz), r12=2.f*(qy*qz-qw*qx);
            float r20=2.f*(qx*qz-qw*qy), r21=2.f*(qy*qz+qw*qx), r22=1.f-2.f*(qx*qx+qy*qy);
            float s0=scal[g*3], s1=scal[g*3+1], s2=scal[g*3+2];
            float m00=r00*s0, m01=r01*s1, m02=r02*s2;
            float m10=r10*s0, m11=r11*s1, m12=r12*s2;
            float m20=r20*s0, m21=r21*s1, m22=r22*s2;
            // U3 = Rw @ M  (cov2d = (J U3)(J U3)^T)
            float u00=R00*m00+R01*m10+R02*m20, u01=R00*m01+R01*m11+R02*m21, u02=R00*m02+R01*m12+R02*m22;
            float u10=R10*m00+R11*m10+R12*m20, u11=R10*m01+R11*m11+R12*m21, u12=R10*m02+R11*m12+R12*m22;
            float u20=R20*m00+R21*m10+R22*m20, u21=R20*m01+R21*m11+R22*m21, u22=R20*m02+R21*m12+R22*m22;
            float x0=xyz[g*3], x1=xyz[g*3+1], x2=xyz[g*3+2];
            float p0=R00*x0+R01*x1+R02*x2+t0;
            float p1=R10*x0+R11*x1+R12*x2+t1;
            float p2=R20*x0+R21*x1+R22*x2+t2;
            float z = p2;
            float zs = fmaxf(z, 1e-4f);
            float invzs = 1.0f/zs;
            float u = fx*p0*invzs + cx;
            float v = fy*p1*invzs + cy;
            float j00 = fx*invzs, j02 = -fx*p0*invzs*invzs;
            float j11 = fy*invzs, j12 = -fy*p1*invzs*invzs;
            float T00=j00*u00+j02*u20, T01=j00*u01+j02*u21, T02=j00*u02+j02*u22;
            float T10=j11*u10+j12*u20, T11=j11*u11+j12*u21, T12=j11*u12+j12*u22;
            float a  = T00*T00+T01*T01+T02*T02 + 0.3f;
            float bb = T00*T10+T01*T11+T02*T12;
            float c  = T10*T10+T11*T11+T12*T12 + 0.3f;
            float dt = a*c - bb*bb;
            bool  vdet = dt > 1e-12f;
            float inv = 1.0f/(vdet ? dt : 1.0f);
            bool valid = (z > nearf) && (z < farf) && vdet;
            pu[g]=u;      pv[g]=v;
            pia[g]=c*inv; pib[g]=-bb*inv; pic[g]=a*inv;
            pop[g]= valid ? opac[g] : 0.0f;
            pcr[g]=fmaxf(0.28209479177387814f*feat[g*3+0]+0.5f, 0.0f);
            pcg[g]=fmaxf(0.28209479177387814f*feat[g*3+1]+0.5f, 0.0f);
            pcb[g]=fmaxf(0.28209479177387814f*feat[g*3+2]+0.5f, 0.0f);
            pz[g]=z;
        } else {
            pop[g]=0.0f; pz[g]=3.4e38f;
        }
    }
    __syncthreads();

    // ---- phase 2: cull vs this tile, append survivor keys ----
    const int tilex = blockIdx.x & (IMG_W/TILE - 1);
    const int tiley = blockIdx.x / (IMG_W/TILE);
    const float tx0 = tilex*TILE + 0.5f, tx1 = tx0 + (TILE-1);
    const float ty0 = tiley*TILE + 0.5f, ty1 = ty0 + (TILE-1);

    #pragma unroll
    for (int i = 0; i < NMAX/256; ++i) {
        const int g = i*256 + t;
        float op = pop[g];
        float tau = 2.0f*__logf(255.0f*op) + 0.02f;  // conservative eps
        if (tau > 0.0f) {
            float ia = pia[g], ib = pib[g], ic = pic[g];
            float u = pu[g], v = pv[g];
            float detC = ia*ic - ib*ib;          // 1/det(cov2d) > 0 when valid
            float inv  = 1.0f/detC;
            float ru = sqrtf(tau * ic * inv);    // sqrt(tau * Sigma_xx)
            float rv = sqrtf(tau * ia * inv);    // sqrt(tau * Sigma_yy)
            if ((u + ru >= tx0) && (u - ru <= tx1) &&
                (v + rv >= ty0) && (v - rv <= ty1)) {
                int p = atomicAdd(&cnt, 1);
                keys[p] = ((unsigned long long)__float_as_uint(pz[g]) << 32)
                          | (unsigned int)g;     // z>near>0 -> bit-monotone
            }
        }
    }
    __syncthreads();
    const int M = cnt;

    // ---- phase 3: stable rank-counting sort of survivor keys ----
    for (int s = t; s < M; s += 256) {
        const unsigned long long k = keys[s];
        int rank = 0;
        for (int j = 0; j < M; ++j) rank += (keys[j] < k) ? 1 : 0;
        sidx[rank] = (int)(k & 0xffffffffu);
    }
    __syncthreads();

    // ---- phase 4: per-pixel front-to-back compositing (threads 0..63) ----
    if (t < TILE*TILE) {
        const int x = tilex*TILE + (t & (TILE-1));
        const int y = tiley*TILE + (t / TILE);
        const float px = x + 0.5f, py = y + 0.5f;
        float T = 1.0f, rr=0.f, gg=0.f, bbv=0.f, dd=0.f;
        for (int j = 0; j < M; ++j) {
            const int g = sidx[j];                     // uniform -> broadcast
            float dx = px - pu[g], dy = py - pv[g];
            float pw = -0.5f*(pia[g]*dx*dx + pic[g]*dy*dy) - pib[g]*dx*dy;
            float al = fminf(pop[g]*__expf(fminf(pw, 0.0f)), 0.99f);
            if (pw <= 0.0f && al >= (1.0f/255.0f)) {
                float w = T*al;
                rr += w*pcr[g]; gg += w*pcg[g]; bbv += w*pcb[g]; dd += w*pz[g];
                T *= (1.0f - al);
                if (T < 1e-5f) break;
            }
        }
        const int HW = IMG_W*IMG_H;
        const int pix = y*IMG_W + x;
        out[0*HW+pix] = rr;
        out[1*HW+pix] = gg;
        out[2*HW+pix] = bbv;
        out[3*HW+pix] = dd;
    }
}

extern "C" void kernel_launch(void* const* d_in, const int* in_sizes, int n_in,
                              void* d_out, int out_size, void* d_ws, size_t ws_size,
                              hipStream_t stream) {
    const float* xyz  = (const float*)d_in[0];
    const float* feat = (const float*)d_in[1];
    const float* scal = (const float*)d_in[2];
    const float* rot  = (const float*)d_in[3];
    const float* opac = (const float*)d_in[4];
    const float* c2w  = (const float*)d_in[5];
    const float* intr = (const float*)d_in[6];
    const int*   nearp = (const int*)d_in[10];
    const int*   farp  = (const int*)d_in[11];
    float* out = (float*)d_out;
    const int N = in_sizes[0] / 3;

    const int ntiles = (IMG_W/TILE) * (IMG_H/TILE);  // 256 blocks
    fused_render_kernel<<<ntiles, 256, 0, stream>>>(
        xyz, feat, scal, rot, opac, c2w, intr, nearp, farp, out, N);
}

// Round 4
// 105.503 us; speedup vs baseline: 3.6258x; 1.0071x over previous
//
#include <hip/hip_runtime.h>
#include <hip/hip_bf16.h>
#include <math.h>

// Problem constants (fixed by the reference file): B=1, N=2048, V=1, H=W=128.
#define NMAX 2048
#define IMG_W 128
#define IMG_H 128
#define TILE 8            // 8x8 pixel tiles -> 256 blocks = 1 per CU
#define CAP  1024         // max survivors per tile (measured ~100; 10x margin)

// ---------------------------------------------------------------------------
// Single fused kernel, one block per 8x8 tile:
//  Phase 1 (fused preprocess+cull): each thread processes 8 gaussians fully
//    in registers; only gaussians whose alpha>=1/255 ellipse bbox touches the
//    tile are appended (atomicAdd) to a compact LDS SoA. Key packs
//    (z_bits<<21 | orig_idx<<10 | slot): z>near>0 so float bits are
//    unsigned-monotone; orig_idx tie-break reproduces stable jnp.argsort;
//    slot (unique) makes keys distinct so rank-counting is exact.
//  Phase 2: rank-counting sort of the M survivor keys (M ~ 100).
//  Phase 3: lanes 0..63 composite their pixel front-to-back via sidx
//    indirection (uniform -> LDS broadcast), early exit at T<1e-5.
// LDS: 10*CAP*4 + CAP*8 + CAP*4 + 4 = ~53 KB.
// ---------------------------------------------------------------------------
__global__ __launch_bounds__(256) void fused_render_kernel(
    const float* __restrict__ xyz, const float* __restrict__ feat,
    const float* __restrict__ scal, const float* __restrict__ rot,
    const float* __restrict__ opac, const float* __restrict__ c2w,
    const float* __restrict__ intr, const int* __restrict__ nearp,
    const int* __restrict__ farp, float* __restrict__ out, int N)
{
    __shared__ float su[CAP], sv[CAP], sia[CAP], sib[CAP], sic[CAP],
                     sop[CAP], scr[CAP], scg[CAP], scb[CAP], sz[CAP];
    __shared__ unsigned long long keys[CAP];
    __shared__ int sidx[CAP];
    __shared__ int cnt;

    const int t = threadIdx.x;
    if (t == 0) cnt = 0;
    __syncthreads();

    // ---- camera setup (uniform; folds to scalar ops) ----
    const float A00=c2w[0], A01=c2w[1], A02=c2w[2],  b0=c2w[3];
    const float A10=c2w[4], A11=c2w[5], A12=c2w[6],  b1=c2w[7];
    const float A20=c2w[8], A21=c2w[9], A22=c2w[10], b2=c2w[11];
    const float detA = A00*(A11*A22-A12*A21) - A01*(A10*A22-A12*A20)
                     + A02*(A10*A21-A11*A20);
    const float id = 1.0f/detA;
    const float R00 =  (A11*A22-A12*A21)*id;
    const float R01 = -(A01*A22-A02*A21)*id;
    const float R02 =  (A01*A12-A02*A11)*id;
    const float R10 = -(A10*A22-A12*A20)*id;
    const float R11 =  (A00*A22-A02*A20)*id;
    const float R12 = -(A00*A12-A02*A10)*id;
    const float R20 =  (A10*A21-A11*A20)*id;
    const float R21 = -(A00*A21-A01*A20)*id;
    const float R22 =  (A00*A11-A01*A10)*id;
    const float t0 = -(R00*b0 + R01*b1 + R02*b2);
    const float t1 = -(R10*b0 + R11*b1 + R12*b2);
    const float t2 = -(R20*b0 + R21*b1 + R22*b2);
    const float fx=intr[0], fy=intr[1], cx=intr[2], cy=intr[3];
    const float nearf = (float)nearp[0], farf = (float)farp[0];

    const int tilex = blockIdx.x & (IMG_W/TILE - 1);
    const int tiley = blockIdx.x / (IMG_W/TILE);
    const float tx0 = tilex*TILE + 0.5f, tx1 = tx0 + (TILE-1);
    const float ty0 = tiley*TILE + 0.5f, ty1 = ty0 + (TILE-1);

    // ---- phase 1: preprocess + cull + append survivors ----
    #pragma unroll
    for (int i = 0; i < NMAX/256; ++i) {
        const int g = i*256 + t;
        if (g >= N) continue;
        const float4 q4 = *(const float4*)(rot + g*4);
        float qw=q4.x, qx=q4.y, qy=q4.z, qz=q4.w;
        float iq = 1.0f/(sqrtf(qw*qw+qx*qx+qy*qy+qz*qz) + 1e-8f);
        qw*=iq; qx*=iq; qy*=iq; qz*=iq;
        float r00=1.f-2.f*(qy*qy+qz*qz), r01=2.f*(qx*qy-qw*qz), r02=2.f*(qx*qz+qw*qy);
        float r10=2.f*(qx*qy+qw*qz), r11=1.f-2.f*(qx*qx+qz*qz), r12=2.f*(qy*qz-qw*qx);
        float r20=2.f*(qx*qz-qw*qy), r21=2.f*(qy*qz+qw*qx), r22=1.f-2.f*(qx*qx+qy*qy);
        float s0=scal[g*3], s1=scal[g*3+1], s2=scal[g*3+2];
        float m00=r00*s0, m01=r01*s1, m02=r02*s2;
        float m10=r10*s0, m11=r11*s1, m12=r12*s2;
        float m20=r20*s0, m21=r21*s1, m22=r22*s2;
        // U3 = Rw @ M  (cov2d = (J U3)(J U3)^T)
        float u00=R00*m00+R01*m10+R02*m20, u01=R00*m01+R01*m11+R02*m21, u02=R00*m02+R01*m12+R02*m22;
        float u10=R10*m00+R11*m10+R12*m20, u11=R10*m01+R11*m11+R12*m21, u12=R10*m02+R11*m12+R12*m22;
        float u20=R20*m00+R21*m10+R22*m20, u21=R20*m01+R21*m11+R22*m21, u22=R20*m02+R21*m12+R22*m22;
        float x0=xyz[g*3], x1=xyz[g*3+1], x2=xyz[g*3+2];
        float p0=R00*x0+R01*x1+R02*x2+t0;
        float p1=R10*x0+R11*x1+R12*x2+t1;
        float p2=R20*x0+R21*x1+R22*x2+t2;
        float z = p2;
        float zs = fmaxf(z, 1e-4f);
        float invzs = 1.0f/zs;
        float u = fx*p0*invzs + cx;
        float v = fy*p1*invzs + cy;
        float j00 = fx*invzs, j02 = -fx*p0*invzs*invzs;
        float j11 = fy*invzs, j12 = -fy*p1*invzs*invzs;
        float T00=j00*u00+j02*u20, T01=j00*u01+j02*u21, T02=j00*u02+j02*u22;
        float T10=j11*u10+j12*u20, T11=j11*u11+j12*u21, T12=j11*u12+j12*u22;
        float a  = T00*T00+T01*T01+T02*T02 + 0.3f;
        float bb = T00*T10+T01*T11+T02*T12;
        float c  = T10*T10+T11*T11+T12*T12 + 0.3f;
        float dt = a*c - bb*bb;
        bool  vdet = dt > 1e-12f;
        float inv = 1.0f/(vdet ? dt : 1.0f);
        bool valid = (z > nearf) && (z < farf) && vdet;
        float op = valid ? opac[g] : 0.0f;

        // cull: alpha>=1/255 ellipse bbox vs tile (conic PD when valid)
        float tau = 2.0f*__logf(255.0f*op) + 0.02f;   // conservative eps
        if (tau <= 0.0f) continue;
        float ia =  c*inv, ib = -bb*inv, ic = a*inv;
        float detC = ia*ic - ib*ib;                   // = 1/det(cov2d) > 0
        float dci  = 1.0f/detC;
        float ru = sqrtf(tau * ic * dci);             // sqrt(tau*Sigma_xx)
        float rv = sqrtf(tau * ia * dci);             // sqrt(tau*Sigma_yy)
        if ((u + ru < tx0) || (u - ru > tx1) ||
            (v + rv < ty0) || (v - rv > ty1)) continue;

        int p = atomicAdd(&cnt, 1);
        if (p < CAP) {
            su[p]=u; sv[p]=v; sia[p]=ia; sib[p]=ib; sic[p]=ic; sop[p]=op;
            scr[p]=fmaxf(0.28209479177387814f*feat[g*3+0]+0.5f, 0.0f);
            scg[p]=fmaxf(0.28209479177387814f*feat[g*3+1]+0.5f, 0.0f);
            scb[p]=fmaxf(0.28209479177387814f*feat[g*3+2]+0.5f, 0.0f);
            sz[p]=z;
            keys[p] = ((unsigned long long)__float_as_uint(z) << 21)
                    | ((unsigned long long)g << 10)
                    | (unsigned long long)p;
        }
    }
    __syncthreads();
    const int M = min(cnt, CAP);

    // ---- phase 2: stable rank-counting sort of survivor keys ----
    for (int s = t; s < M; s += 256) {
        const unsigned long long k = keys[s];
        int rank = 0;
        for (int j = 0; j < M; ++j) rank += (keys[j] < k) ? 1 : 0;
        sidx[rank] = (int)(k & (CAP-1));
    }
    __syncthreads();

    // ---- phase 3: per-pixel front-to-back compositing (lanes 0..63) ----
    if (t < TILE*TILE) {
        const int x = tilex*TILE + (t & (TILE-1));
        const int y = tiley*TILE + (t / TILE);
        const float px = x + 0.5f, py = y + 0.5f;
        float T = 1.0f, rr=0.f, gg=0.f, bbv=0.f, dd=0.f;
        for (int j = 0; j < M; ++j) {
            const int s = sidx[j];                    // uniform -> broadcast
            float dx = px - su[s], dy = py - sv[s];
            float pw = -0.5f*(sia[s]*dx*dx + sic[s]*dy*dy) - sib[s]*dx*dy;
            float al = fminf(sop[s]*__expf(fminf(pw, 0.0f)), 0.99f);
            if (pw <= 0.0f && al >= (1.0f/255.0f)) {
                float w = T*al;
                rr += w*scr[s]; gg += w*scg[s]; bbv += w*scb[s]; dd += w*sz[s];
                T *= (1.0f - al);
                if (T < 1e-5f) break;
            }
        }
        const int HW = IMG_W*IMG_H;
        const int pix = y*IMG_W + x;
        out[0*HW+pix] = rr;
        out[1*HW+pix] = gg;
        out[2*HW+pix] = bbv;
        out[3*HW+pix] = dd;
    }
}

extern "C" void kernel_launch(void* const* d_in, const int* in_sizes, int n_in,
                              void* d_out, int out_size, void* d_ws, size_t ws_size,
                              hipStream_t stream) {
    const float* xyz  = (const float*)d_in[0];
    const float* feat = (const float*)d_in[1];
    const float* scal = (const float*)d_in[2];
    const float* rot  = (const float*)d_in[3];
    const float* opac = (const float*)d_in[4];
    const float* c2w  = (const float*)d_in[5];
    const float* intr = (const float*)d_in[6];
    const int*   nearp = (const int*)d_in[10];
    const int*   farp  = (const int*)d_in[11];
    float* out = (float*)d_out;
    const int N = in_sizes[0] / 3;

    const int ntiles = (IMG_W/TILE) * (IMG_H/TILE);  // 256 blocks
    fused_render_kernel<<<ntiles, 256, 0, stream>>>(
        xyz, feat, scal, rot, opac, c2w, intr, nearp, farp, out, N);
}